// Round 2
// baseline (800.660 us; speedup 1.0000x reference)
//
#include <hip/hip_runtime.h>
#include <math.h>

// CapsuleLayer dynamic routing, MI355X.
// Shapes: inp[16,1024,64], W[1,1024,32,64,64], b[1,1024,32,64] -> out vj[16,32,64]
#define B_  16
#define P_  1024
#define J_  32
#define D_  64
#define DP_ 64

typedef float v4 __attribute__((ext_vector_type(4)));

// ---------------------------------------------------------------------------
// K1: u[b,p,j,d] = sum_e inp[b,p,e] * W[p,j,e,d] + bias[p,j,d]
// One block per p. 256 threads; thread owns (j in {jg, jg+16}, d quad d0..d0+3)
// for ALL 16 b -> 128 fp32 accumulators in registers. W element loaded once,
// reused 16x (once per b). W float4 loads: wave reads 1KB/instr, coalesced.
// Memory-bound on the 512MB W stream (~19 TB/s VALU-side demand vs 6.3 supply).
// ---------------------------------------------------------------------------
__global__ __launch_bounds__(256, 2) void k_umat(const float* __restrict__ x,
                                                 const float* __restrict__ W,
                                                 const float* __restrict__ bias,
                                                 float* __restrict__ u) {
  const int p  = blockIdx.x;
  const int t  = threadIdx.x;
  const int jg = t >> 4;          // 0..15
  const int d0 = (t & 15) << 2;   // 0,4,...,60

  // inp staged in LDS as sx[e*17 + b]  (stride 17 -> conflict-free writes)
  __shared__ float sx[64 * 17];
  {
    const int e = t & 63, b4 = t >> 6;  // e = lane, b4 = wave id
#pragma unroll
    for (int i = 0; i < 4; ++i) {
      const int b = b4 * 4 + i;
      sx[e * 17 + b] = x[(size_t)(b * P_ + p) * DP_ + e];
    }
  }
  __syncthreads();

  const float* Wp = W + (size_t)p * (J_ * DP_ * D_);
  const float* bp = bias + (size_t)p * (J_ * D_);

  v4 acc0[16], acc1[16];
  const v4 bv0 = *(const v4*)&bp[jg * D_ + d0];
  const v4 bv1 = *(const v4*)&bp[(jg + 16) * D_ + d0];
#pragma unroll
  for (int b = 0; b < 16; ++b) { acc0[b] = bv0; acc1[b] = bv1; }

  const float* w0 = Wp + (size_t)jg * (DP_ * D_) + d0;
  const float* w1 = Wp + (size_t)(jg + 16) * (DP_ * D_) + d0;

#pragma unroll 2
  for (int e = 0; e < 64; ++e) {
    const v4 wa = *(const v4*)&w0[e * D_];
    const v4 wb = *(const v4*)&w1[e * D_];
#pragma unroll
    for (int b = 0; b < 16; ++b) {
      const float xv = sx[e * 17 + b];   // broadcast read, conflict-free
      acc0[b] += wa * xv;
      acc1[b] += wb * xv;
    }
  }

#pragma unroll
  for (int b = 0; b < 16; ++b) {
    const size_t base = (size_t)(b * P_ + p) * (J_ * D_);
    *(v4*)&u[base + jg * D_ + d0]        = acc0[b];
    *(v4*)&u[base + (jg + 16) * D_ + d0] = acc1[b];
  }
}

// ---------------------------------------------------------------------------
// K2: vj0[b,j,:] = squash( (1/32) * sum_p u[b,p,j,:] )   (it-0: cij = 1/J)
// Block per (b,j). 256 threads: 16 p-groups x 16 d-quads.
// ---------------------------------------------------------------------------
__global__ __launch_bounds__(256) void k_mean_squash(const float* __restrict__ u,
                                                     float* __restrict__ vj) {
  const int b = blockIdx.x >> 5, j = blockIdx.x & 31;
  const int t = threadIdx.x;
  const int d0 = (t & 15) << 2, pg = t >> 4;

  v4 s = {0.f, 0.f, 0.f, 0.f};
  for (int p = pg; p < P_; p += 16)
    s += *(const v4*)&u[((size_t)(b * P_ + p) * J_ + j) * D_ + d0];

  __shared__ __align__(16) float sred[16][64];
  *(v4*)&sred[pg][d0] = s;
  __syncthreads();

  if (t < 64) {
    float v = 0.f;
#pragma unroll
    for (int g = 0; g < 16; ++g) v += sred[g][t];
    v *= (1.0f / 32.0f);
    float s2 = v * v;
#pragma unroll
    for (int o = 32; o; o >>= 1) s2 += __shfl_xor(s2, o);
    const float f = sqrtf(s2) / (1.0f + s2);
    vj[(size_t)blockIdx.x * D_ + t] = v * f;
  }
}

// ---------------------------------------------------------------------------
// K3/K5: one routing pass. Block per (b, pb); pb indexes 16-p chunks
// (1024 blocks -> 4/CU to shorten the per-p serial sync chain).
// Per p: agreement a[j] = sum_d u*vj ; bij_new = bij_old + a (FIRST: old=0);
// cij = softmax_j(bij_new); acc[j,d] += cij[j]*u. Partials out per block.
// ---------------------------------------------------------------------------
template <int FIRST>
__global__ __launch_bounds__(256) void k_route(const float* __restrict__ u,
                                               const float* __restrict__ vj,
                                               float* __restrict__ bij,
                                               float* __restrict__ part) {
  const int b = blockIdx.x >> 6, pb = blockIdx.x & 63;
  const int t = threadIdx.x;
  const int jg = t >> 4, d0 = (t & 15) << 2;
  const int j0 = jg, j1 = jg + 16;

  __shared__ __align__(16) float svj[J_ * D_];
  __shared__ float sag[32];
  __shared__ float sc[2][32];

  for (int i = t; i < J_ * D_; i += 256) svj[i] = vj[b * (J_ * D_) + i];
  __syncthreads();

  const v4 vv0 = *(const v4*)&svj[j0 * D_ + d0];
  const v4 vv1 = *(const v4*)&svj[j1 * D_ + d0];
  v4 acc0 = {0.f, 0.f, 0.f, 0.f}, acc1 = {0.f, 0.f, 0.f, 0.f};

  for (int pi = 0; pi < 16; ++pi) {
    const int p = pb * 16 + pi;
    const size_t ub = (size_t)(b * P_ + p) * (J_ * D_);
    const v4 u0 = *(const v4*)&u[ub + j0 * D_ + d0];
    const v4 u1 = *(const v4*)&u[ub + j1 * D_ + d0];

    float bold = 0.f;
    if (!FIRST && t < 32) bold = bij[(size_t)(b * P_ + p) * J_ + t];

    // agreement: reduce u*vj over the 64 d's (16 lanes x 4 components)
    const v4 q0 = u0 * vv0, q1 = u1 * vv1;
    float a0 = q0[0] + q0[1] + q0[2] + q0[3];
    float a1 = q1[0] + q1[1] + q1[2] + q1[3];
#pragma unroll
    for (int o = 8; o; o >>= 1) {
      a0 += __shfl_xor(a0, o);
      a1 += __shfl_xor(a1, o);
    }
    if ((t & 15) == 0) { sag[j0] = a0; sag[j1] = a1; }
    __syncthreads();

    if (t < 32) {
      const float bn = bold + sag[t];
      bij[(size_t)(b * P_ + p) * J_ + t] = bn;
      // softmax over 32 j's held by lanes 0..31 of wave 0
      float m = bn;
#pragma unroll
      for (int o = 16; o; o >>= 1) m = fmaxf(m, __shfl_xor(m, o));
      const float e = __expf(bn - m);
      float sum = e;
#pragma unroll
      for (int o = 16; o; o >>= 1) sum += __shfl_xor(sum, o);
      sc[pi & 1][t] = e / sum;
    }
    __syncthreads();

    const float c0 = sc[pi & 1][j0];
    const float c1 = sc[pi & 1][j1];
    acc0 += u0 * c0;
    acc1 += u1 * c1;
  }

  const size_t pbase = (size_t)blockIdx.x * (J_ * D_);
  *(v4*)&part[pbase + j0 * D_ + d0] = acc0;
  *(v4*)&part[pbase + j1 * D_ + d0] = acc1;
}

// ---------------------------------------------------------------------------
// K4/K6: vj[b,j,:] = squash( sum_pb part[b,pb,j,:] ). Block per (b,j), 1 wave.
// ---------------------------------------------------------------------------
__global__ __launch_bounds__(64) void k_red_squash(const float* __restrict__ part,
                                                   float* __restrict__ outp) {
  const int b = blockIdx.x >> 5, j = blockIdx.x & 31;
  const int d = threadIdx.x;
  float s = 0.f;
#pragma unroll 8
  for (int pb = 0; pb < 64; ++pb)
    s += part[(size_t)(b * 64 + pb) * (J_ * D_) + j * D_ + d];
  float s2 = s * s;
#pragma unroll
  for (int o = 32; o; o >>= 1) s2 += __shfl_xor(s2, o);
  const float f = sqrtf(s2) / (1.0f + s2);
  outp[(size_t)blockIdx.x * D_ + d] = s * f;
}

// ---------------------------------------------------------------------------
extern "C" void kernel_launch(void* const* d_in, const int* in_sizes, int n_in,
                              void* d_out, int out_size, void* d_ws, size_t ws_size,
                              hipStream_t stream) {
  const float* x    = (const float*)d_in[0];
  const float* W    = (const float*)d_in[1];
  const float* bias = (const float*)d_in[2];
  float* out = (float*)d_out;

  // Workspace layout (bytes):
  //   u    : 16*1024*32*64*4      = 128 MiB
  //   bij  : 16*1024*32*4         =   2 MiB
  //   part : 16*64*32*64*4        =   8 MiB
  //   vj0/vj1 : 2 * 16*32*64*4    = 256 KiB
  char* ws = (char*)d_ws;
  float* u    = (float*)(ws);
  float* bij  = (float*)(ws + (size_t)134217728);
  float* part = (float*)(ws + (size_t)134217728 + 2097152);
  float* vj0  = (float*)(ws + (size_t)134217728 + 2097152 + 8388608);
  float* vj1  = vj0 + (B_ * J_ * D_);

  k_umat<<<P_, 256, 0, stream>>>(x, W, bias, u);
  k_mean_squash<<<B_ * J_, 256, 0, stream>>>(u, vj0);
  k_route<1><<<B_ * 64, 256, 0, stream>>>(u, vj0, bij, part);
  k_red_squash<<<B_ * J_, 64, 0, stream>>>(part, vj1);
  k_route<0><<<B_ * 64, 256, 0, stream>>>(u, vj1, bij, part);
  k_red_squash<<<B_ * J_, 64, 0, stream>>>(part, out);
}

// Round 3
// 790.146 us; speedup vs baseline: 1.0133x; 1.0133x over previous
//
#include <hip/hip_runtime.h>
#include <math.h>

// CapsuleLayer dynamic routing, MI355X.
// inp[16,1024,64], W[1,1024,32,64,64], bias[1,1024,32,64] -> vj[16,32,64]
#define B_  16
#define P_  1024
#define J_  32
#define D_  64
#define DP_ 64
#define TILE_ 2048   // J_*D_ floats per (b,p) u-tile (= 512 v4)

typedef float v4 __attribute__((ext_vector_type(4)));

__device__ __forceinline__ v4 ntload4(const float* p) {
  return __builtin_nontemporal_load((const v4*)p);
}

// ---------------------------------------------------------------------------
// K1: u[b,p,j,d] = sum_e inp[b,p,e]*W[p,j,e,d] + bias[p,j,d]
// 1 block per p, 512 threads: thread t owns (j = t>>4, dquad = t&15) for all
// 16 b -> 16 v4 accumulators (64 VGPR). W element read exactly once per block,
// nontemporal (don't evict u from L3). Memory-bound on the 512MB W stream.
// ---------------------------------------------------------------------------
__global__ __launch_bounds__(512, 4) void k_umat(const float* __restrict__ x,
                                                 const float* __restrict__ W,
                                                 const float* __restrict__ bias,
                                                 float* __restrict__ u) {
  const int p  = blockIdx.x;
  const int t  = threadIdx.x;     // 0..511
  const int j  = t >> 4;          // 0..31
  const int d0 = (t & 15) << 2;   // 0..60

  __shared__ float sx[64][17];    // sx[e][b], pad 17 -> conflict-free
  {
    const int i = t;              // two strided passes cover 1024 elems
#pragma unroll
    for (int it = 0; it < 2; ++it) {
      const int idx = i + it * 512;
      const int b = idx >> 6, e = idx & 63;       // consecutive e -> coalesced
      sx[e][b] = x[(size_t)(b * P_ + p) * DP_ + e];
    }
  }
  __syncthreads();

  const float* wp = W + (size_t)p * (J_ * DP_ * D_) + (size_t)j * (DP_ * D_) + d0;
  const v4 bv = *(const v4*)&bias[(size_t)p * (J_ * D_) + j * D_ + d0];

  v4 acc[16];
#pragma unroll
  for (int b = 0; b < 16; ++b) acc[b] = bv;

#pragma unroll 4
  for (int e = 0; e < 64; ++e) {
    const v4 w = ntload4(wp + e * D_);
#pragma unroll
    for (int b = 0; b < 16; ++b) acc[b] += w * sx[e][b];   // broadcast LDS read
  }

#pragma unroll
  for (int b = 0; b < 16; ++b) {
    *(v4*)&u[(size_t)(b * P_ + p) * TILE_ + j * D_ + d0] = acc[b];
  }
}

// ---------------------------------------------------------------------------
// K2: vj0[b,j,:] = squash( (1/32) * sum_p u[b,p,j,:] )   (it-0: cij = 1/J)
// ---------------------------------------------------------------------------
__global__ __launch_bounds__(256) void k_mean_squash(const float* __restrict__ u,
                                                     float* __restrict__ vj) {
  const int b = blockIdx.x >> 5, j = blockIdx.x & 31;
  const int t = threadIdx.x;
  const int d0 = (t & 15) << 2, pg = t >> 4;

  v4 s = {0.f, 0.f, 0.f, 0.f};
  for (int p = pg; p < P_; p += 16)
    s += *(const v4*)&u[(size_t)(b * P_ + p) * TILE_ + j * D_ + d0];

  __shared__ __align__(16) float sred[16][64];
  *(v4*)&sred[pg][d0] = s;
  __syncthreads();

  if (t < 64) {
    float v = 0.f;
#pragma unroll
    for (int g = 0; g < 16; ++g) v += sred[g][t];
    v *= (1.0f / 32.0f);
    float s2 = v * v;
#pragma unroll
    for (int o = 32; o; o >>= 1) s2 += __shfl_xor(s2, o);
    const float f = sqrtf(s2) / (1.0f + s2);
    vj[(size_t)blockIdx.x * D_ + t] = v * f;
  }
}

// ---------------------------------------------------------------------------
// K3/K5: routing pass, wave-autonomous (no LDS, no __syncthreads).
// Flat map of the (b,p) u-tile: v4 index m = k*64 + l  (k=0..7, l=lane)
//   -> j = 4k + (l>>4), dquad = l&15. Loads fully coalesced (1KB/wave instr).
// Agreement a[j]: dot per lane + shfl_xor over lq (1,2,4,8).
// Softmax over 32 j's: 8 local values + shfl_xor 16,32. All in-register.
// Each wave owns 8 consecutive p's; per-wave partial written to part[].
// Grid: 512 blocks x 256 thr = 2048 waves = (b, pw=0..127).
// ---------------------------------------------------------------------------
template <int FIRST>
__global__ __launch_bounds__(256) void k_route(const float* __restrict__ u,
                                               const float* __restrict__ vj,
                                               float* __restrict__ bij,
                                               float* __restrict__ part) {
  const int b     = blockIdx.x >> 5;
  const int chunk = blockIdx.x & 31;
  const int w     = threadIdx.x >> 6;
  const int l     = threadIdx.x & 63;
  const int l4    = l >> 4;      // j residue mod 4
  const int lq    = l & 15;      // d-quad
  const int pw    = chunk * 4 + w;          // 0..127
  const int p0    = pw * 8;

  // vj fragment: vv[k] = vj[b, j=4k+l4, dquad lq]
  const v4* vjv = (const v4*)(vj + (size_t)b * TILE_);
  v4 vv[8];
#pragma unroll
  for (int k = 0; k < 8; ++k) vv[k] = vjv[(4 * k + l4) * 16 + lq];

  v4 acc[8];
#pragma unroll
  for (int k = 0; k < 8; ++k) acc[k] = (v4){0.f, 0.f, 0.f, 0.f};

  for (int pi = 0; pi < 8; ++pi) {
    const int p = p0 + pi;
    const size_t bp = (size_t)(b * P_ + p);
    const v4* up = (const v4*)(u + bp * TILE_);

    v4 uf[8];
#pragma unroll
    for (int k = 0; k < 8; ++k) uf[k] = up[k * 64 + l];

    // agreement partials: dot over this lane's 4 d's
    float a[8];
#pragma unroll
    for (int k = 0; k < 8; ++k) {
      const v4 q = uf[k] * vv[k];
      a[k] = (q[0] + q[1]) + (q[2] + q[3]);
    }
    // reduce over the 16 lanes sharing (l>>4): full a[j] replicated
#pragma unroll
    for (int o = 1; o <= 8; o <<= 1) {
#pragma unroll
      for (int k = 0; k < 8; ++k) a[k] += __shfl_xor(a[k], o);
    }

    float bn[8];
    if (FIRST) {
#pragma unroll
      for (int k = 0; k < 8; ++k) bn[k] = a[k];
      if (lq == 0) {   // store bij for pass 2 (4 lanes x 8 k = 32 j's)
#pragma unroll
        for (int k = 0; k < 8; ++k) bij[bp * J_ + 4 * k + l4] = bn[k];
      }
    } else {
#pragma unroll
      for (int k = 0; k < 8; ++k) bn[k] = a[k] + bij[bp * J_ + 4 * k + l4];
    }

    // softmax over 32 j's
    float m = bn[0];
#pragma unroll
    for (int k = 1; k < 8; ++k) m = fmaxf(m, bn[k]);
    m = fmaxf(m, __shfl_xor(m, 16));
    m = fmaxf(m, __shfl_xor(m, 32));
    float ex[8], s = 0.f;
#pragma unroll
    for (int k = 0; k < 8; ++k) { ex[k] = __expf(bn[k] - m); s += ex[k]; }
    s += __shfl_xor(s, 16);
    s += __shfl_xor(s, 32);
    const float inv = 1.0f / s;
#pragma unroll
    for (int k = 0; k < 8; ++k) acc[k] += uf[k] * (ex[k] * inv);
  }

  v4* pp = (v4*)(part + (size_t)(b * 128 + pw) * TILE_);
#pragma unroll
  for (int k = 0; k < 8; ++k) pp[k * 64 + l] = acc[k];
}

// ---------------------------------------------------------------------------
// K4/K6: vj[b,j,:] = squash( sum_pw part[b,pw,j,:] ). Block per (b,j), 1 wave.
// ---------------------------------------------------------------------------
__global__ __launch_bounds__(64) void k_red_squash(const float* __restrict__ part,
                                                   float* __restrict__ outp) {
  const int b = blockIdx.x >> 5, j = blockIdx.x & 31;
  const int d = threadIdx.x;
  float s = 0.f;
#pragma unroll 8
  for (int pw = 0; pw < 128; ++pw)
    s += part[(size_t)(b * 128 + pw) * TILE_ + j * D_ + d];
  float s2 = s * s;
#pragma unroll
  for (int o = 32; o; o >>= 1) s2 += __shfl_xor(s2, o);
  const float f = sqrtf(s2) / (1.0f + s2);
  outp[(size_t)blockIdx.x * D_ + d] = s * f;
}

// ---------------------------------------------------------------------------
extern "C" void kernel_launch(void* const* d_in, const int* in_sizes, int n_in,
                              void* d_out, int out_size, void* d_ws, size_t ws_size,
                              hipStream_t stream) {
  const float* x    = (const float*)d_in[0];
  const float* W    = (const float*)d_in[1];
  const float* bias = (const float*)d_in[2];
  float* out = (float*)d_out;

  // ws layout: u 128MiB | bij 2MiB | part 16MiB | vj0,vj1 256KiB
  char* ws = (char*)d_ws;
  float* u    = (float*)(ws);
  float* bij  = (float*)(ws + (size_t)134217728);
  float* part = (float*)(ws + (size_t)134217728 + 2097152);
  float* vj0  = (float*)(ws + (size_t)134217728 + 2097152 + 16777216);
  float* vj1  = vj0 + (B_ * J_ * D_);

  k_umat<<<P_, 512, 0, stream>>>(x, W, bias, u);
  k_mean_squash<<<B_ * J_, 256, 0, stream>>>(u, vj0);
  k_route<1><<<512, 256, 0, stream>>>(u, vj0, bij, part);
  k_red_squash<<<B_ * J_, 64, 0, stream>>>(part, vj1);
  k_route<0><<<512, 256, 0, stream>>>(u, vj1, bij, part);
  k_red_squash<<<B_ * J_, 64, 0, stream>>>(part, out);
}